// Round 9
// baseline (722.674 us; speedup 1.0000x reference)
//
#include <hip/hip_runtime.h>
#include <hip/hip_bf16.h>

#define N_NODES 20000
#define F_IN 512

typedef __attribute__((ext_vector_type(8))) short short8;
typedef __attribute__((ext_vector_type(4))) float f32x4;

// ---------------------------------------------------------------- helpers
__device__ __forceinline__ ushort f2bf(float f) {
    uint u = __float_as_uint(f);
    u += 0x7FFF + ((u >> 16) & 1);
    return (ushort)(u >> 16);
}
__device__ __forceinline__ float bf2f(ushort h) { return __uint_as_float((uint)h << 16); }

__device__ __forceinline__ void gload_lds16(const void* g, void* l) {
    __builtin_amdgcn_global_load_lds(
        (const __attribute__((address_space(1))) void*)g,
        (__attribute__((address_space(3))) void*)l, 16, 0, 0);
}

__device__ __forceinline__ f32x4 shfl_xor4(f32x4 v, int m) {
    f32x4 r;
#pragma unroll
    for (int i = 0; i < 4; i++) r[i] = __shfl_xor(v[i], m);
    return r;
}

// ---------------------------------------------------------------- CSR build
__global__ void zero_int_k(int* p, int n) {
    int i = blockIdx.x * blockDim.x + threadIdx.x;
    if (i < n) p[i] = 0;
}

__global__ void hist_k(const int* __restrict__ ei, int E0, int N, int* __restrict__ deg) {
    int e = blockIdx.x * blockDim.x + threadIdx.x;
    int Etot = E0 + N;
    if (e >= Etot) return;
    int dst = (e < E0) ? ei[E0 + e] : (e - E0);
    atomicAdd(&deg[dst], 1);
}

__global__ __launch_bounds__(1024) void scan_k(const int* __restrict__ deg, int* __restrict__ rp,
                                               int* __restrict__ fp, float* __restrict__ dis,
                                               int N, int Etot) {
    __shared__ int part[1024];
    int tid = threadIdx.x;
    int chunk = (N + 1023) / 1024;
    int lo = tid * chunk, hi = min(lo + chunk, N);
    int s = 0;
    for (int i = lo; i < hi; i++) s += deg[i];
    part[tid] = s;
    __syncthreads();
    for (int off = 1; off < 1024; off <<= 1) {
        int t = 0;
        if (tid >= off) t = part[tid - off];
        __syncthreads();
        part[tid] += t;
        __syncthreads();
    }
    int run = part[tid] - s;
    for (int i = lo; i < hi; i++) {
        rp[i] = run; fp[i] = run;
        int d = deg[i];
        dis[i] = (d > 0) ? rsqrtf((float)d) : 0.f;
        run += d;
    }
    if (tid == 1023) { rp[N] = Etot; fp[N] = Etot; }
}

__global__ void scatter_k(const int* __restrict__ ei, int E0, int N, int* __restrict__ fp,
                          int* __restrict__ csr_src) {
    int e = blockIdx.x * blockDim.x + threadIdx.x;
    int Etot = E0 + N;
    if (e >= Etot) return;
    int src, dst;
    if (e < E0) { src = ei[e]; dst = ei[E0 + e]; }
    else        { src = e - E0; dst = src; }
    int pos = atomicAdd(&fp[dst], 1);
    csr_src[pos] = src;
}

// ---------------------------------------------------------------- BN affine prep
__global__ void bnprep_k(const float* __restrict__ g, const float* __restrict__ b,
                         const float* __restrict__ rm, const float* __restrict__ rv,
                         float* __restrict__ sc, float* __restrict__ sh, int n) {
    int i = blockIdx.x * blockDim.x + threadIdx.x;
    if (i >= n) return;
    float s = g[i] * rsqrtf(rv[i] + 1e-5f);
    sc[i] = s;
    sh[i] = b[i] - rm[i] * s;
}

// ---------------------------------------------------------------- A split
__global__ void splitA_k(const float* __restrict__ x, const float* __restrict__ sc,
                         const float* __restrict__ sh, ushort* __restrict__ Ah,
                         ushort* __restrict__ Al, int M, int Mpad) {
    size_t i4 = (size_t)blockIdx.x * blockDim.x + threadIdx.x;
    size_t base = i4 * 4;
    if (base >= (size_t)Mpad * 512) return;
    int row = (int)(base >> 9);
    ushort4 ah = {0, 0, 0, 0}, al = {0, 0, 0, 0};
    if (row < M) {
        float4 v = *(const float4*)&x[base];
        int c = (int)(base & 511);
        float f0 = v.x * sc[c] + sh[c];
        float f1 = v.y * sc[c + 1] + sh[c + 1];
        float f2 = v.z * sc[c + 2] + sh[c + 2];
        float f3 = v.w * sc[c + 3] + sh[c + 3];
        ah.x = f2bf(f0); al.x = f2bf(f0 - bf2f(ah.x));
        ah.y = f2bf(f1); al.y = f2bf(f1 - bf2f(ah.y));
        ah.z = f2bf(f2); al.z = f2bf(f2 - bf2f(ah.z));
        ah.w = f2bf(f3); al.w = f2bf(f3 - bf2f(ah.w));
    }
    *(ushort4*)&Ah[base] = ah;
    *(ushort4*)&Al[base] = al;
}

// ---------------------------------------------------------------- B prep
__global__ __launch_bounds__(256) void splitBt_k(const float* __restrict__ W1, const float* __restrict__ Ws,
                                                 ushort* __restrict__ Bth, ushort* __restrict__ Btl) {
    __shared__ float tile[64][65];
    int n0 = blockIdx.x * 64;
    int k0 = blockIdx.y * 64;
    int t = threadIdx.x;
    int a = t >> 6, b = t & 63;
#pragma unroll
    for (int i = 0; i < 16; i++) {
        int kk = a + i * 4, nn = b;
        int gk = k0 + kk, gn = n0 + nn;
        float v;
        if (gn < 512)      v = W1[(size_t)gk * 512 + gn];
        else if (gn < 576) v = Ws[(size_t)gk * 64 + (gn - 512)];
        else               v = 0.f;
        tile[kk][nn] = v;
    }
    __syncthreads();
#pragma unroll
    for (int i = 0; i < 16; i++) {
        int nn = a + i * 4, kk = b;
        float v = tile[kk][nn];
        ushort hi = f2bf(v);
        ushort lo = f2bf(v - bf2f(hi));
        Bth[(size_t)(n0 + nn) * 512 + k0 + kk] = hi;
        Btl[(size_t)(n0 + nn) * 512 + k0 + kk] = lo;
    }
}

// ---------------------------------------------------------------- fused MFMA GEMM (proven: rounds 6/7)
__global__ __launch_bounds__(256) void mfma_gemm_k(
    const ushort* __restrict__ Ah, const ushort* __restrict__ Al,
    const ushort* __restrict__ Bth, const ushort* __restrict__ Btl,
    const float* __restrict__ bs, const float* __restrict__ as1, const float* __restrict__ ad1,
    float* __restrict__ h1, float* __restrict__ skip,
    float* __restrict__ ss1, float* __restrict__ sd1,
    int M, int K) {
    __shared__ ushort A_s[128 * 64];
    __shared__ ushort B_s[128 * 64];
    __shared__ float s1buf[128], s2buf[128];
    int t = threadIdx.x;
    int w = t >> 6, l = t & 63;

    int nwg = gridDim.x;
    int q = nwg >> 3, r = nwg & 7;
    int xcd = blockIdx.x & 7, lid = blockIdx.x >> 3;
    int wg = (xcd < r) ? xcd * (q + 1) + lid : r * (q + 1) + (xcd - r) * q + lid;
    int by = wg / 5, bx = wg % 5;
    int bm = by * 128;
    int n0 = bx * 128;
    int r0 = (w & 1) * 64, c0 = (w >> 1) * 64;

    f32x4 acc[4][4] = {};

    int sl = (t & 7) ^ ((t >> 3) & 7);
    const ushort* aArr = (sl < 4) ? Ah : Al;
    const ushort* bArr = (sl < 4) ? Bth : Btl;
    int ko = (sl & 3) * 8;
    size_t asrc[4], bsrc[4];
#pragma unroll
    for (int c = 0; c < 4; c++) {
        int rr = c * 32 + (t >> 3);
        asrc[c] = (size_t)(bm + rr) * 512 + ko;
        bsrc[c] = (size_t)(n0 + rr) * 512 + ko;
    }
    int d0 = t * 8;

    for (int kt = 0; kt < K; kt += 32) {
#pragma unroll
        for (int c = 0; c < 4; c++) gload_lds16(aArr + asrc[c] + kt, &A_s[c * 2048 + d0]);
#pragma unroll
        for (int c = 0; c < 4; c++) gload_lds16(bArr + bsrc[c] + kt, &B_s[c * 2048 + d0]);
        __syncthreads();

        short8 ah[4], al4[4], bh[4], bl[4];
        int lr = l & 15, kg = l >> 4;
        int spa = kg ^ (lr & 7);
#pragma unroll
        for (int f = 0; f < 4; f++) {
            int ra = (r0 + f * 16 + lr) * 64;
            ah[f]  = *(const short8*)&A_s[ra + spa * 8];
            al4[f] = *(const short8*)&A_s[ra + (spa ^ 4) * 8];
            int rb = (c0 + f * 16 + lr) * 64;
            bh[f] = *(const short8*)&B_s[rb + spa * 8];
            bl[f] = *(const short8*)&B_s[rb + (spa ^ 4) * 8];
        }
#pragma unroll
        for (int fm = 0; fm < 4; fm++)
#pragma unroll
            for (int fn = 0; fn < 4; fn++) {
                acc[fm][fn] = __builtin_amdgcn_mfma_f32_16x16x32_bf16(ah[fm], bh[fn], acc[fm][fn], 0, 0, 0);
                acc[fm][fn] = __builtin_amdgcn_mfma_f32_16x16x32_bf16(ah[fm], bl[fn], acc[fm][fn], 0, 0, 0);
                acc[fm][fn] = __builtin_amdgcn_mfma_f32_16x16x32_bf16(al4[fm], bh[fn], acc[fm][fn], 0, 0, 0);
            }
        __syncthreads();
    }

    int lr = l & 15, kg = l >> 4;
#pragma unroll
    for (int fm = 0; fm < 4; fm++) {
        int row_base = bm + r0 + fm * 16 + kg * 4;
#pragma unroll
        for (int fn = 0; fn < 4; fn++) {
            int col = n0 + c0 + fn * 16 + lr;
#pragma unroll
            for (int r2 = 0; r2 < 4; r2++) {
                int row = row_base + r2;
                if (row < M) {
                    float v = acc[fm][fn][r2];
                    if (col < 512) h1[(size_t)row * 512 + col] = v;
                    else if (col < 576) skip[(size_t)row * 64 + (col - 512)] = fmaxf(v + bs[col - 512], 0.f);
                }
            }
        }
    }

    if (t < 128) { s1buf[t] = 0.f; s2buf[t] = 0.f; }
    __syncthreads();
    if (bx < 4) {
        float aw_[4], dw_[4];
#pragma unroll
        for (int fn = 0; fn < 4; fn++) {
            int col = n0 + c0 + fn * 16 + lr;
            aw_[fn] = as1[col];
            dw_[fn] = ad1[col];
        }
#pragma unroll
        for (int fm = 0; fm < 4; fm++)
#pragma unroll
            for (int r2 = 0; r2 < 4; r2++) {
                float p1 = acc[fm][0][r2] * aw_[0] + acc[fm][1][r2] * aw_[1] +
                           acc[fm][2][r2] * aw_[2] + acc[fm][3][r2] * aw_[3];
                float p2 = acc[fm][0][r2] * dw_[0] + acc[fm][1][r2] * dw_[1] +
                           acc[fm][2][r2] * dw_[2] + acc[fm][3][r2] * dw_[3];
#pragma unroll
                for (int off = 1; off < 16; off <<= 1) {
                    p1 += __shfl_xor(p1, off);
                    p2 += __shfl_xor(p2, off);
                }
                if (lr == 0) {
                    int rloc = r0 + fm * 16 + kg * 4 + r2;
                    atomicAdd(&s1buf[rloc], p1);
                    atomicAdd(&s2buf[rloc], p2);
                }
            }
    }
    __syncthreads();
    if (bx < 4 && t < 128 && bm + t < M) {
        ss1[(size_t)(bm + t) * 4 + bx] = s1buf[t];
        sd1[(size_t)(bm + t) * 4 + bx] = s2buf[t];
    }
}

// ================================================================ K1: GAT1 agg (8 nodes/block, wave-per-node) -> x1 in LDS -> hg1 = x1 @ Wg1
__global__ __launch_bounds__(256) void gat1_gcn1_k(
    const float* __restrict__ h1, const float* __restrict__ ss1, const float* __restrict__ sd1,
    const float* __restrict__ b1, const float* __restrict__ g1, const float* __restrict__ be1,
    const int* __restrict__ rp, const int* __restrict__ csr,
    const float* __restrict__ Wg1, float* __restrict__ hg1, int N) {
    __shared__ __align__(16) float x1s[8][128];
    int t = threadIdx.x;
    int l = t & 63, wv = t >> 6;
    int hh = l >> 4, lr = l & 15;

    // ---- phase A: per wave, 2 nodes
    for (int i = 0; i < 2; i++) {
        int nl = wv * 2 + i;
        int n = blockIdx.x * 8 + nl;
        if (n < N) {
            int e0 = rp[n], deg = rp[n + 1] - e0;
            float sdv = sd1[n * 4 + hh];
            float m = -1e30f, s = 0.f;
            for (int k = lr; k < deg; k += 16) {
                int src = csr[e0 + k];
                float e = ss1[src * 4 + hh] + sdv;
                e = (e > 0.f) ? e : 0.2f * e;
                float mn = fmaxf(m, e);
                s = s * __expf(m - mn) + __expf(e - mn);
                m = mn;
            }
#pragma unroll
            for (int off = 8; off; off >>= 1) {
                float mo = __shfl_xor(m, off), so = __shfl_xor(s, off);
                float mn = fmaxf(m, mo);
                s = s * __expf(m - mn) + so * __expf(mo - mn);
                m = mn;
            }
            s += 1e-16f;
            f32x4 a0 = {0, 0, 0, 0}, a1 = {0, 0, 0, 0};
            for (int k = 0; k < deg; k++) {
                int src = csr[e0 + k];
                float e = ss1[src * 4 + hh] + sdv;
                e = (e > 0.f) ? e : 0.2f * e;
                float al = __expf(e - m) / s;
                const float* hp = h1 + (size_t)src * 512 + hh * 128 + lr * 8;
                a0 += al * *(const f32x4*)hp;
                a1 += al * *(const f32x4*)(hp + 4);
            }
            // head mean
            a0 += shfl_xor4(a0, 16); a1 += shfl_xor4(a1, 16);
            a0 += shfl_xor4(a0, 32); a1 += shfl_xor4(a1, 32);
            f32x4 v0 = a0 * 0.25f + *(const f32x4*)&b1[lr * 8];
            f32x4 v1 = a1 * 0.25f + *(const f32x4*)&b1[lr * 8 + 4];
            float s1 = v0[0] + v0[1] + v0[2] + v0[3] + v1[0] + v1[1] + v1[2] + v1[3];
#pragma unroll
            for (int off = 8; off; off >>= 1) s1 += __shfl_xor(s1, off);
            float mu = s1 * (1.f / 128.f);
            f32x4 d0 = v0 - mu, d1 = v1 - mu;
            float s2 = d0[0]*d0[0] + d0[1]*d0[1] + d0[2]*d0[2] + d0[3]*d0[3] +
                       d1[0]*d1[0] + d1[1]*d1[1] + d1[2]*d1[2] + d1[3]*d1[3];
#pragma unroll
            for (int off = 8; off; off >>= 1) s2 += __shfl_xor(s2, off);
            float rs = rsqrtf(s2 * (1.f / 128.f) + 1e-5f);
            if (l < 16) {
                f32x4 g4a = *(const f32x4*)&g1[lr * 8], g4b = *(const f32x4*)&g1[lr * 8 + 4];
                f32x4 e4a = *(const f32x4*)&be1[lr * 8], e4b = *(const f32x4*)&be1[lr * 8 + 4];
                f32x4 y0, y1;
#pragma unroll
                for (int j = 0; j < 4; j++) {
                    y0[j] = fmaxf(d0[j] * rs * g4a[j] + e4a[j], 0.f);
                    y1[j] = fmaxf(d1[j] * rs * g4b[j] + e4b[j], 0.f);
                }
                *(f32x4*)&x1s[nl][lr * 8] = y0;
                *(f32x4*)&x1s[nl][lr * 8 + 4] = y1;
            }
        }
    }
    __syncthreads();

    // ---- phase B: hg1[8 rows] = x1s @ Wg1  (128x128)
    int c = t & 127, rh = t >> 7;
    float acc[4] = {};
    for (int k = 0; k < 128; k += 4) {
        float w0 = Wg1[(size_t)k * 128 + c];
        float w1 = Wg1[(size_t)(k + 1) * 128 + c];
        float w2 = Wg1[(size_t)(k + 2) * 128 + c];
        float w3 = Wg1[(size_t)(k + 3) * 128 + c];
#pragma unroll
        for (int r = 0; r < 4; r++) {
            f32x4 xv = *(const f32x4*)&x1s[rh * 4 + r][k];
            acc[r] += xv[0] * w0 + xv[1] * w1 + xv[2] * w2 + xv[3] * w3;
        }
    }
    for (int r = 0; r < 4; r++) {
        int n = blockIdx.x * 8 + rh * 4 + r;
        if (n < N) hg1[(size_t)n * 128 + c] = acc[r];
    }
}

// ================================================================ K2: GCN1 agg -> x1g (LDS+global) -> h2 = x1g @ W2 + GAT2 scores
__global__ __launch_bounds__(256) void gcn1_gat2gemm_k(
    const float* __restrict__ hg1, const float* __restrict__ dis, const float* __restrict__ bg1,
    const int* __restrict__ rp, const int* __restrict__ csr,
    const float* __restrict__ W2, const float* __restrict__ as2, const float* __restrict__ ad2,
    float* __restrict__ x1g, float* __restrict__ h2,
    float* __restrict__ ss2, float* __restrict__ sd2, int N) {
    __shared__ __align__(16) float xs[8][128];
    int t = threadIdx.x;
    int l = t & 63, wv = t >> 6;
    int ep = l >> 5, c4 = (l & 31) * 4;

    for (int i = 0; i < 2; i++) {
        int nl = wv * 2 + i;
        int n = blockIdx.x * 8 + nl;
        if (n < N) {
            int e0 = rp[n], deg = rp[n + 1] - e0;
            float dn = dis[n];
            f32x4 acc = {0, 0, 0, 0};
            for (int k = ep; k < deg; k += 2) {
                int src = csr[e0 + k];
                acc += (dis[src] * dn) * *(const f32x4*)(hg1 + (size_t)src * 128 + c4);
            }
            acc += shfl_xor4(acc, 32);
            if (l < 32) {
                f32x4 b4 = *(const f32x4*)&bg1[c4];
                f32x4 y;
#pragma unroll
                for (int j = 0; j < 4; j++) y[j] = fmaxf(acc[j] + b4[j], 0.f);
                *(f32x4*)&xs[nl][c4] = y;
                *(f32x4*)(x1g + (size_t)n * 128 + c4) = y;
            }
        }
    }
    __syncthreads();

    int c = t & 127, rh = t >> 7;
    int head = (t >> 6) & 1;
    float asv = as2[c], adv = ad2[c];
    float acc[4] = {};
    for (int k = 0; k < 128; k += 4) {
        float w0 = W2[(size_t)k * 128 + c];
        float w1 = W2[(size_t)(k + 1) * 128 + c];
        float w2 = W2[(size_t)(k + 2) * 128 + c];
        float w3 = W2[(size_t)(k + 3) * 128 + c];
#pragma unroll
        for (int r = 0; r < 4; r++) {
            f32x4 xv = *(const f32x4*)&xs[rh * 4 + r][k];
            acc[r] += xv[0] * w0 + xv[1] * w1 + xv[2] * w2 + xv[3] * w3;
        }
    }
    for (int r = 0; r < 4; r++) {
        int n = blockIdx.x * 8 + rh * 4 + r;
        if (n < N) h2[(size_t)n * 128 + c] = acc[r];
        float p1 = acc[r] * asv, p2 = acc[r] * adv;
#pragma unroll
        for (int off = 1; off < 64; off <<= 1) {
            p1 += __shfl_xor(p1, off);
            p2 += __shfl_xor(p2, off);
        }
        if (l == 0 && n < N) {
            ss2[(size_t)n * 2 + head] = p1;
            sd2[(size_t)n * 2 + head] = p2;
        }
    }
}

// ================================================================ K3: GAT2 agg -> x2 in LDS -> hg2 = x2 @ Wg2
__global__ __launch_bounds__(256) void gat2_gcn2gemm_k(
    const float* __restrict__ h2, const float* __restrict__ ss2, const float* __restrict__ sd2,
    const float* __restrict__ b2, const float* __restrict__ g2, const float* __restrict__ be2,
    const int* __restrict__ rp, const int* __restrict__ csr,
    const float* __restrict__ Wg2, float* __restrict__ hg2, int N) {
    __shared__ __align__(16) float xs[8][64];
    int t = threadIdx.x;
    int l = t & 63, wv = t >> 6;
    int hh = l >> 5, lr = l & 31, c2 = lr * 2;

    for (int i = 0; i < 2; i++) {
        int nl = wv * 2 + i;
        int n = blockIdx.x * 8 + nl;
        if (n < N) {
            int e0 = rp[n], deg = rp[n + 1] - e0;
            float sdv = sd2[n * 2 + hh];
            float m = -1e30f, s = 0.f;
            for (int k = lr; k < deg; k += 32) {
                int src = csr[e0 + k];
                float e = ss2[src * 2 + hh] + sdv;
                e = (e > 0.f) ? e : 0.2f * e;
                float mn = fmaxf(m, e);
                s = s * __expf(m - mn) + __expf(e - mn);
                m = mn;
            }
#pragma unroll
            for (int off = 16; off; off >>= 1) {
                float mo = __shfl_xor(m, off), so = __shfl_xor(s, off);
                float mn = fmaxf(m, mo);
                s = s * __expf(m - mn) + so * __expf(mo - mn);
                m = mn;
            }
            s += 1e-16f;
            float a0 = 0.f, a1 = 0.f;
            for (int k = 0; k < deg; k++) {
                int src = csr[e0 + k];
                float e = ss2[src * 2 + hh] + sdv;
                e = (e > 0.f) ? e : 0.2f * e;
                float al = __expf(e - m) / s;
                const float* hp = h2 + (size_t)src * 128 + hh * 64 + c2;
                a0 += al * hp[0];
                a1 += al * hp[1];
            }
            a0 += __shfl_xor(a0, 32);
            a1 += __shfl_xor(a1, 32);
            float v0 = a0 * 0.5f + b2[c2];
            float v1 = a1 * 0.5f + b2[c2 + 1];
            float s1 = v0 + v1;
#pragma unroll
            for (int off = 16; off; off >>= 1) s1 += __shfl_xor(s1, off);
            float mu = s1 * (1.f / 64.f);
            float d0 = v0 - mu, d1 = v1 - mu;
            float s2 = d0 * d0 + d1 * d1;
#pragma unroll
            for (int off = 16; off; off >>= 1) s2 += __shfl_xor(s2, off);
            float rs = rsqrtf(s2 * (1.f / 64.f) + 1e-5f);
            if (l < 32) {
                float y0 = fmaxf(d0 * rs * g2[c2] + be2[c2], 0.f);
                float y1 = fmaxf(d1 * rs * g2[c2 + 1] + be2[c2 + 1], 0.f);
                float2 y = {y0, y1};
                *(float2*)&xs[nl][c2] = y;
            }
        }
    }
    __syncthreads();

    int c = t & 63, rg = t >> 6;
    float acc[2] = {};
    for (int k = 0; k < 64; k += 4) {
        float w0 = Wg2[(size_t)k * 64 + c];
        float w1 = Wg2[(size_t)(k + 1) * 64 + c];
        float w2 = Wg2[(size_t)(k + 2) * 64 + c];
        float w3 = Wg2[(size_t)(k + 3) * 64 + c];
#pragma unroll
        for (int r = 0; r < 2; r++) {
            f32x4 xv = *(const f32x4*)&xs[rg * 2 + r][k];
            acc[r] += xv[0] * w0 + xv[1] * w1 + xv[2] * w2 + xv[3] * w3;
        }
    }
    for (int r = 0; r < 2; r++) {
        int n = blockIdx.x * 8 + rg * 2 + r;
        if (n < N) hg2[(size_t)n * 64 + c] = acc[r];
    }
}

// ================================================================ K4: gcn_agg2 -> fusion+LN -> classifier (round-7 proven)
__global__ __launch_bounds__(256) void final_fused_k(
    const float* __restrict__ hg2, const float* __restrict__ dis, const float* __restrict__ bg2,
    const int* __restrict__ rp, const int* __restrict__ csr_src,
    const float* __restrict__ x1g, const float* __restrict__ Wf, const float* __restrict__ bf,
    const float* __restrict__ skip, const float* __restrict__ g3, const float* __restrict__ be3,
    const float* __restrict__ Wc1, const float* __restrict__ bc1, const float* __restrict__ gbn,
    const float* __restrict__ bbn, const float* __restrict__ rmb, const float* __restrict__ rvb,
    const float* __restrict__ Wc2, const float* __restrict__ bc2, float* __restrict__ out, int N) {
    int wv = threadIdx.x >> 6;
    int t  = threadIdx.x & 63;
    int n = blockIdx.x * 4 + wv;
    __shared__ __align__(16) float cat_s[4][192];
    __shared__ float fbuf_s[4][64];
    __shared__ float hbuf_s[4][32];
    if (n >= N) return;

    int e0 = rp[n], deg = rp[n + 1] - e0;
    float dn = dis[n];
    int ep = t >> 4, o = (t & 15) * 4;
    f32x4 acc = {0, 0, 0, 0};
    for (int k = ep; k < deg; k += 4) {
        int s = csr_src[e0 + k];
        f32x4 v = *(const f32x4*)(hg2 + (size_t)s * 64 + o);
        acc += (dis[s] * dn) * v;
    }
    acc += shfl_xor4(acc, 32);
    acc += shfl_xor4(acc, 16);
    if (t < 16) {
        f32x4 b4 = *(const f32x4*)&bg2[o];
        f32x4 xv;
#pragma unroll
        for (int i = 0; i < 4; i++) xv[i] = fmaxf(acc[i] + b4[i], 0.f);
        *(f32x4*)&cat_s[wv][128 + o] = xv;
    }
    if (t < 32) *(f32x4*)&cat_s[wv][t * 4] = *(const f32x4*)(x1g + (size_t)n * 128 + t * 4);
    float fa = bf[t];
    const float* cat = cat_s[wv];
    for (int j = 0; j < 192; j++) fa += cat[j] * Wf[j * 64 + t];
    fa = fmaxf(fa, 0.f) + skip[(size_t)n * 64 + t];
    float t1 = fa;
#pragma unroll
    for (int off = 1; off < 64; off <<= 1) t1 += __shfl_xor(t1, off);
    float mu = t1 * (1.f / 64.f);
    float d = fa - mu;
    float t2 = d * d;
#pragma unroll
    for (int off = 1; off < 64; off <<= 1) t2 += __shfl_xor(t2, off);
    float var = t2 * (1.f / 64.f);
    fbuf_s[wv][t] = d * rsqrtf(var + 1e-5f) * g3[t] + be3[t];
    if (t < 32) {
        float a = bc1[t];
        for (int j = 0; j < 64; j++) a += fbuf_s[wv][j] * Wc1[j * 32 + t];
        a = (a - rmb[t]) * rsqrtf(rvb[t] + 1e-5f) * gbn[t] + bbn[t];
        hbuf_s[wv][t] = fmaxf(a, 0.f);
    }
    if (t < 5) {
        float a = bc2[t];
        for (int j = 0; j < 32; j++) a += hbuf_s[wv][j] * Wc2[j * 5 + t];
        out[(size_t)n * 5 + t] = a;
    }
}

// ================================================================ launch
extern "C" void kernel_launch(void* const* d_in, const int* in_sizes, int n_in,
                              void* d_out, int out_size, void* d_ws, size_t ws_size,
                              hipStream_t stream) {
    const float* x   = (const float*)d_in[0];
    const int*   ei  = (const int*)d_in[1];
    const float* gin = (const float*)d_in[2];
    const float* bti = (const float*)d_in[3];
    const float* rmi = (const float*)d_in[4];
    const float* rvi = (const float*)d_in[5];
    const float* W1  = (const float*)d_in[6];
    const float* as1 = (const float*)d_in[7];
    const float* ad1 = (const float*)d_in[8];
    const float* b1  = (const float*)d_in[9];
    const float* Wg1 = (const float*)d_in[10];
    const float* bg1 = (const float*)d_in[11];
    const float* W2  = (const float*)d_in[12];
    const float* as2 = (const float*)d_in[13];
    const float* ad2 = (const float*)d_in[14];
    const float* b2  = (const float*)d_in[15];
    const float* Wg2 = (const float*)d_in[16];
    const float* bg2 = (const float*)d_in[17];
    const float* Ws  = (const float*)d_in[18];
    const float* bs  = (const float*)d_in[19];
    const float* Wf  = (const float*)d_in[20];
    const float* bf  = (const float*)d_in[21];
    const float* g1  = (const float*)d_in[22];
    const float* be1 = (const float*)d_in[23];
    const float* g2  = (const float*)d_in[24];
    const float* be2 = (const float*)d_in[25];
    const float* g3  = (const float*)d_in[26];
    const float* be3 = (const float*)d_in[27];
    const float* Wc1 = (const float*)d_in[28];
    const float* bc1 = (const float*)d_in[29];
    const float* gbn = (const float*)d_in[30];
    const float* bbn = (const float*)d_in[31];
    const float* rmb = (const float*)d_in[32];
    const float* rvb = (const float*)d_in[33];
    const float* Wc2 = (const float*)d_in[34];
    const float* bc2 = (const float*)d_in[35];
    float* out = (float*)d_out;

    const int N = in_sizes[0] / F_IN;          // 20000
    const int E0 = in_sizes[1] / 2;            // 160000
    const int Etot = E0 + N;                   // 180000
    const int Mpad = 20096;                    // 157*128

    // ---- workspace carve-up
    char* wp = (char*)d_ws;
    auto alloc = [&](size_t bytes) -> void* {
        void* p = (void*)wp;
        wp += (bytes + 255) & ~(size_t)255;
        return p;
    };
    float* h1   = (float*)alloc((size_t)N * 512 * 4);     // dedicated (read by K1 only)
    ushort* Ah  = (ushort*)alloc((size_t)Mpad * 512 * 2); // Ah+Al contiguous; dead after GEMM
    ushort* Al  = (ushort*)alloc((size_t)Mpad * 512 * 2);
    ushort* Bth = (ushort*)alloc((size_t)640 * 512 * 2);
    ushort* Btl = (ushort*)alloc((size_t)640 * 512 * 2);
    float* skip = (float*)alloc((size_t)N * 64 * 4);
    float* ss1  = (float*)alloc((size_t)N * 4 * 4);
    float* sd1  = (float*)alloc((size_t)N * 4 * 4);
    float* ss2  = (float*)alloc((size_t)N * 2 * 4);
    float* sd2  = (float*)alloc((size_t)N * 2 * 4);
    float* dis  = (float*)alloc((size_t)N * 4);
    float* sc   = (float*)alloc((size_t)F_IN * 4);
    float* sh   = (float*)alloc((size_t)F_IN * 4);
    int* deg    = (int*)alloc((size_t)N * 4);
    int* rp     = (int*)alloc((size_t)(N + 1) * 4);
    int* fp     = (int*)alloc((size_t)(N + 1) * 4);
    int* csr    = (int*)alloc((size_t)Etot * 4);
    // post-GEMM aliases inside Ah+Al region (41.16 MB; need 35.84 MB)
    float* hg1 = (float*)Ah;            // N*128
    float* x1g = hg1 + (size_t)N * 128; // N*128
    float* h2  = hg1 + (size_t)N * 256; // N*128
    float* hg2 = hg1 + (size_t)N * 384; // N*64

    // ---- CSR build + BN prep + splits
    zero_int_k<<<(N + 255) / 256, 256, 0, stream>>>(deg, N);
    hist_k<<<(Etot + 255) / 256, 256, 0, stream>>>(ei, E0, N, deg);
    scan_k<<<1, 1024, 0, stream>>>(deg, rp, fp, dis, N, Etot);
    scatter_k<<<(Etot + 255) / 256, 256, 0, stream>>>(ei, E0, N, fp, csr);
    bnprep_k<<<2, 256, 0, stream>>>(gin, bti, rmi, rvi, sc, sh, F_IN);
    splitA_k<<<(int)(((size_t)Mpad * 512 / 4 + 255) / 256), 256, 0, stream>>>(x, sc, sh, Ah, Al, N, Mpad);
    splitBt_k<<<dim3(10, 8), 256, 0, stream>>>(W1, Ws, Bth, Btl);

    // ---- fused GEMM: [h1 | skip] + GAT1 scores
    mfma_gemm_k<<<785, 256, 0, stream>>>(Ah, Al, Bth, Btl, bs, as1, ad1, h1, skip, ss1, sd1, N, 512);

    // ---- K1..K4
    gat1_gcn1_k<<<(N + 7) / 8, 256, 0, stream>>>(h1, ss1, sd1, b1, g1, be1, rp, csr, Wg1, hg1, N);
    gcn1_gat2gemm_k<<<(N + 7) / 8, 256, 0, stream>>>(hg1, dis, bg1, rp, csr, W2, as2, ad2,
                                                     x1g, h2, ss2, sd2, N);
    gat2_gcn2gemm_k<<<(N + 7) / 8, 256, 0, stream>>>(h2, ss2, sd2, b2, g2, be2, rp, csr, Wg2, hg2, N);
    final_fused_k<<<(N + 3) / 4, 256, 0, stream>>>(hg2, dis, bg2, rp, csr, x1g, Wf, bf, skip, g3, be3,
                                                   Wc1, bc1, gbn, bbn, rmb, rvb, Wc2, bc2, out, N);
}

// Round 11
// 550.918 us; speedup vs baseline: 1.3118x; 1.3118x over previous
//
#include <hip/hip_runtime.h>
#include <hip/hip_bf16.h>

#define N_NODES 20000
#define F_IN 512

typedef __attribute__((ext_vector_type(8))) short short8;
typedef __attribute__((ext_vector_type(4))) float f32x4;

// ---------------------------------------------------------------- helpers
__device__ __forceinline__ ushort f2bf(float f) {
    uint u = __float_as_uint(f);
    u += 0x7FFF + ((u >> 16) & 1);
    return (ushort)(u >> 16);
}
__device__ __forceinline__ float bf2f(ushort h) { return __uint_as_float((uint)h << 16); }

__device__ __forceinline__ void gload_lds16(const void* g, void* l) {
    __builtin_amdgcn_global_load_lds(
        (const __attribute__((address_space(1))) void*)g,
        (__attribute__((address_space(3))) void*)l, 16, 0, 0);
}

__device__ __forceinline__ f32x4 shfl_xor4(f32x4 v, int m) {
    f32x4 r;
#pragma unroll
    for (int i = 0; i < 4; i++) r[i] = __shfl_xor(v[i], m);
    return r;
}

// ---------------------------------------------------------------- CSR build
__global__ void zero_int_k(int* p, int n) {
    int i = blockIdx.x * blockDim.x + threadIdx.x;
    if (i < n) p[i] = 0;
}

__global__ void hist_k(const int* __restrict__ ei, int E0, int N, int* __restrict__ deg) {
    int e = blockIdx.x * blockDim.x + threadIdx.x;
    int Etot = E0 + N;
    if (e >= Etot) return;
    int dst = (e < E0) ? ei[E0 + e] : (e - E0);
    atomicAdd(&deg[dst], 1);
}

__global__ __launch_bounds__(1024) void scan_k(const int* __restrict__ deg, int* __restrict__ rp,
                                               int* __restrict__ fp, float* __restrict__ dis,
                                               int N, int Etot) {
    __shared__ int part[1024];
    int tid = threadIdx.x;
    int chunk = (N + 1023) / 1024;
    int lo = tid * chunk, hi = min(lo + chunk, N);
    int s = 0;
    for (int i = lo; i < hi; i++) s += deg[i];
    part[tid] = s;
    __syncthreads();
    for (int off = 1; off < 1024; off <<= 1) {
        int t = 0;
        if (tid >= off) t = part[tid - off];
        __syncthreads();
        part[tid] += t;
        __syncthreads();
    }
    int run = part[tid] - s;
    for (int i = lo; i < hi; i++) {
        rp[i] = run; fp[i] = run;
        int d = deg[i];
        dis[i] = (d > 0) ? rsqrtf((float)d) : 0.f;
        run += d;
    }
    if (tid == 1023) { rp[N] = Etot; fp[N] = Etot; }
}

__global__ void scatter_k(const int* __restrict__ ei, int E0, int N, int* __restrict__ fp,
                          int* __restrict__ csr_src) {
    int e = blockIdx.x * blockDim.x + threadIdx.x;
    int Etot = E0 + N;
    if (e >= Etot) return;
    int src, dst;
    if (e < E0) { src = ei[e]; dst = ei[E0 + e]; }
    else        { src = e - E0; dst = src; }
    int pos = atomicAdd(&fp[dst], 1);
    csr_src[pos] = src;
}

// ---------------------------------------------------------------- BN affine prep
__global__ void bnprep_k(const float* __restrict__ g, const float* __restrict__ b,
                         const float* __restrict__ rm, const float* __restrict__ rv,
                         float* __restrict__ sc, float* __restrict__ sh, int n) {
    int i = blockIdx.x * blockDim.x + threadIdx.x;
    if (i >= n) return;
    float s = g[i] * rsqrtf(rv[i] + 1e-5f);
    sc[i] = s;
    sh[i] = b[i] - rm[i] * s;
}

// ---------------------------------------------------------------- A split
__global__ void splitA_k(const float* __restrict__ x, const float* __restrict__ sc,
                         const float* __restrict__ sh, ushort* __restrict__ Ah,
                         ushort* __restrict__ Al, int M, int Mpad) {
    size_t i4 = (size_t)blockIdx.x * blockDim.x + threadIdx.x;
    size_t base = i4 * 4;
    if (base >= (size_t)Mpad * 512) return;
    int row = (int)(base >> 9);
    ushort4 ah = {0, 0, 0, 0}, al = {0, 0, 0, 0};
    if (row < M) {
        float4 v = *(const float4*)&x[base];
        int c = (int)(base & 511);
        float f0 = v.x * sc[c] + sh[c];
        float f1 = v.y * sc[c + 1] + sh[c + 1];
        float f2 = v.z * sc[c + 2] + sh[c + 2];
        float f3 = v.w * sc[c + 3] + sh[c + 3];
        ah.x = f2bf(f0); al.x = f2bf(f0 - bf2f(ah.x));
        ah.y = f2bf(f1); al.y = f2bf(f1 - bf2f(ah.y));
        ah.z = f2bf(f2); al.z = f2bf(f2 - bf2f(ah.z));
        ah.w = f2bf(f3); al.w = f2bf(f3 - bf2f(ah.w));
    }
    *(ushort4*)&Ah[base] = ah;
    *(ushort4*)&Al[base] = al;
}

// ---------------------------------------------------------------- B prep
__global__ __launch_bounds__(256) void splitBt_k(const float* __restrict__ W1, const float* __restrict__ Ws,
                                                 ushort* __restrict__ Bth, ushort* __restrict__ Btl) {
    __shared__ float tile[64][65];
    int n0 = blockIdx.x * 64;
    int k0 = blockIdx.y * 64;
    int t = threadIdx.x;
    int a = t >> 6, b = t & 63;
#pragma unroll
    for (int i = 0; i < 16; i++) {
        int kk = a + i * 4, nn = b;
        int gk = k0 + kk, gn = n0 + nn;
        float v;
        if (gn < 512)      v = W1[(size_t)gk * 512 + gn];
        else if (gn < 576) v = Ws[(size_t)gk * 64 + (gn - 512)];
        else               v = 0.f;
        tile[kk][nn] = v;
    }
    __syncthreads();
#pragma unroll
    for (int i = 0; i < 16; i++) {
        int nn = a + i * 4, kk = b;
        float v = tile[kk][nn];
        ushort hi = f2bf(v);
        ushort lo = f2bf(v - bf2f(hi));
        Bth[(size_t)(n0 + nn) * 512 + k0 + kk] = hi;
        Btl[(size_t)(n0 + nn) * 512 + k0 + kk] = lo;
    }
}

// ---------------------------------------------------------------- fused MFMA GEMM (proven rounds 6-7)
__global__ __launch_bounds__(256) void mfma_gemm_k(
    const ushort* __restrict__ Ah, const ushort* __restrict__ Al,
    const ushort* __restrict__ Bth, const ushort* __restrict__ Btl,
    const float* __restrict__ bs, const float* __restrict__ as1, const float* __restrict__ ad1,
    float* __restrict__ h1, float* __restrict__ skip,
    float* __restrict__ ss1, float* __restrict__ sd1,
    int M, int K) {
    __shared__ ushort A_s[128 * 64];
    __shared__ ushort B_s[128 * 64];
    __shared__ float s1buf[128], s2buf[128];
    int t = threadIdx.x;
    int w = t >> 6, l = t & 63;

    int nwg = gridDim.x;
    int q = nwg >> 3, r = nwg & 7;
    int xcd = blockIdx.x & 7, lid = blockIdx.x >> 3;
    int wg = (xcd < r) ? xcd * (q + 1) + lid : r * (q + 1) + (xcd - r) * q + lid;
    int by = wg / 5, bx = wg % 5;
    int bm = by * 128;
    int n0 = bx * 128;
    int r0 = (w & 1) * 64, c0 = (w >> 1) * 64;

    f32x4 acc[4][4] = {};

    int sl = (t & 7) ^ ((t >> 3) & 7);
    const ushort* aArr = (sl < 4) ? Ah : Al;
    const ushort* bArr = (sl < 4) ? Bth : Btl;
    int ko = (sl & 3) * 8;
    size_t asrc[4], bsrc[4];
#pragma unroll
    for (int c = 0; c < 4; c++) {
        int rr = c * 32 + (t >> 3);
        asrc[c] = (size_t)(bm + rr) * 512 + ko;
        bsrc[c] = (size_t)(n0 + rr) * 512 + ko;
    }
    int d0 = t * 8;

    for (int kt = 0; kt < K; kt += 32) {
#pragma unroll
        for (int c = 0; c < 4; c++) gload_lds16(aArr + asrc[c] + kt, &A_s[c * 2048 + d0]);
#pragma unroll
        for (int c = 0; c < 4; c++) gload_lds16(bArr + bsrc[c] + kt, &B_s[c * 2048 + d0]);
        __syncthreads();

        short8 ah[4], al4[4], bh[4], bl[4];
        int lr = l & 15, kg = l >> 4;
        int spa = kg ^ (lr & 7);
#pragma unroll
        for (int f = 0; f < 4; f++) {
            int ra = (r0 + f * 16 + lr) * 64;
            ah[f]  = *(const short8*)&A_s[ra + spa * 8];
            al4[f] = *(const short8*)&A_s[ra + (spa ^ 4) * 8];
            int rb = (c0 + f * 16 + lr) * 64;
            bh[f] = *(const short8*)&B_s[rb + spa * 8];
            bl[f] = *(const short8*)&B_s[rb + (spa ^ 4) * 8];
        }
#pragma unroll
        for (int fm = 0; fm < 4; fm++)
#pragma unroll
            for (int fn = 0; fn < 4; fn++) {
                acc[fm][fn] = __builtin_amdgcn_mfma_f32_16x16x32_bf16(ah[fm], bh[fn], acc[fm][fn], 0, 0, 0);
                acc[fm][fn] = __builtin_amdgcn_mfma_f32_16x16x32_bf16(ah[fm], bl[fn], acc[fm][fn], 0, 0, 0);
                acc[fm][fn] = __builtin_amdgcn_mfma_f32_16x16x32_bf16(al4[fm], bh[fn], acc[fm][fn], 0, 0, 0);
            }
        __syncthreads();
    }

    int lr = l & 15, kg = l >> 4;
#pragma unroll
    for (int fm = 0; fm < 4; fm++) {
        int row_base = bm + r0 + fm * 16 + kg * 4;
#pragma unroll
        for (int fn = 0; fn < 4; fn++) {
            int col = n0 + c0 + fn * 16 + lr;
#pragma unroll
            for (int r2 = 0; r2 < 4; r2++) {
                int row = row_base + r2;
                if (row < M) {
                    float v = acc[fm][fn][r2];
                    if (col < 512) h1[(size_t)row * 512 + col] = v;
                    else if (col < 576) skip[(size_t)row * 64 + (col - 512)] = fmaxf(v + bs[col - 512], 0.f);
                }
            }
        }
    }

    if (t < 128) { s1buf[t] = 0.f; s2buf[t] = 0.f; }
    __syncthreads();
    if (bx < 4) {
        float aw_[4], dw_[4];
#pragma unroll
        for (int fn = 0; fn < 4; fn++) {
            int col = n0 + c0 + fn * 16 + lr;
            aw_[fn] = as1[col];
            dw_[fn] = ad1[col];
        }
#pragma unroll
        for (int fm = 0; fm < 4; fm++)
#pragma unroll
            for (int r2 = 0; r2 < 4; r2++) {
                float p1 = acc[fm][0][r2] * aw_[0] + acc[fm][1][r2] * aw_[1] +
                           acc[fm][2][r2] * aw_[2] + acc[fm][3][r2] * aw_[3];
                float p2 = acc[fm][0][r2] * dw_[0] + acc[fm][1][r2] * dw_[1] +
                           acc[fm][2][r2] * dw_[2] + acc[fm][3][r2] * dw_[3];
#pragma unroll
                for (int off = 1; off < 16; off <<= 1) {
                    p1 += __shfl_xor(p1, off);
                    p2 += __shfl_xor(p2, off);
                }
                if (lr == 0) {
                    int rloc = r0 + fm * 16 + kg * 4 + r2;
                    atomicAdd(&s1buf[rloc], p1);
                    atomicAdd(&s2buf[rloc], p2);
                }
            }
    }
    __syncthreads();
    if (bx < 4 && t < 128 && bm + t < M) {
        ss1[(size_t)(bm + t) * 4 + bx] = s1buf[t];
        sd1[(size_t)(bm + t) * 4 + bx] = s2buf[t];
    }
}

// ---------------------------------------------------------------- small GEMM, W cached in LDS (round 7)
template <int K, int NOUT, bool SC>
__global__ __launch_bounds__(NOUT) void rowgemm_k(const float* __restrict__ X, const float* __restrict__ W,
                                                  float* __restrict__ out,
                                                  const float* __restrict__ a_src, const float* __restrict__ a_dst,
                                                  float* __restrict__ ss, float* __restrict__ sd, int N) {
    __shared__ float Ws[K * NOUT];
    __shared__ float Xs[8][K];
    int c = threadIdx.x;
    for (int i = c; i < K * NOUT; i += NOUT) Ws[i] = W[i];
    float asv = 0.f, adv = 0.f;
    if (SC) { asv = a_src[c]; adv = a_dst[c]; }
    for (int r0 = blockIdx.x * 8; r0 < N; r0 += gridDim.x * 8) {
        int nr = min(8, N - r0);
        __syncthreads();
        for (int i = c; i < nr * K; i += NOUT) Xs[i / K][i % K] = X[(size_t)r0 * K + i];
        __syncthreads();
        float acc[8] = {};
        for (int k = 0; k < K; k++) {
            float w = Ws[k * NOUT + c];
#pragma unroll
            for (int r = 0; r < 8; r++) acc[r] += Xs[r][k] * w;
        }
        for (int r = 0; r < nr; r++) out[(size_t)(r0 + r) * NOUT + c] = acc[r];
        if (SC) {
            int head = c >> 6;
            for (int r = 0; r < nr; r++) {
                float p1 = acc[r] * asv, p2 = acc[r] * adv;
#pragma unroll
                for (int off = 1; off < 64; off <<= 1) {
                    p1 += __shfl_xor(p1, off);
                    p2 += __shfl_xor(p2, off);
                }
                if ((c & 63) == 0) {
                    ss[(size_t)(r0 + r) * 2 + head] = p1;
                    sd[(size_t)(r0 + r) * 2 + head] = p2;
                }
            }
        }
    }
}

// ================================================================ GAT1 agg v2: wave-per-node, shfl-broadcast metadata
__global__ __launch_bounds__(256) void gat1_agg_k(
    const float* __restrict__ h1, const float* __restrict__ ss1, const float* __restrict__ sd1,
    const float* __restrict__ b1, const float* __restrict__ g1, const float* __restrict__ be1,
    const int* __restrict__ rp, const int* __restrict__ csr, float* __restrict__ x1, int N) {
    __shared__ __align__(16) float alds[4][64][4];
    int t = threadIdx.x, l = t & 63, wv = t >> 6;
    int n = blockIdx.x * 4 + wv;
    if (n >= N) return;
    int e0 = rp[n], deg = rp[n + 1] - e0;
    f32x4 sdv4 = *(const f32x4*)&sd1[n * 4];

    // ---- softmax stats (online over 64-edge chunks); cache first chunk in regs
    f32x4 m4, s4;
#pragma unroll
    for (int i = 0; i < 4; i++) { m4[i] = -1e30f; s4[i] = 0.f; }
    int srcF = 0; f32x4 e4F;
    for (int t0 = 0; t0 < deg; t0 += 64) {
        int tl = min(64, deg - t0);
        int src = (l < tl) ? csr[e0 + t0 + l] : 0;
        f32x4 e4;
        if (l < tl) {
            f32x4 ssv = *(const f32x4*)&ss1[(size_t)src * 4];
#pragma unroll
            for (int i = 0; i < 4; i++) {
                float v = ssv[i] + sdv4[i];
                e4[i] = (v > 0.f) ? v : 0.2f * v;
            }
        } else {
#pragma unroll
            for (int i = 0; i < 4; i++) e4[i] = -1e30f;
        }
        if (t0 == 0) { srcF = src; e4F = e4; }
        f32x4 cm = e4;
#pragma unroll
        for (int off = 32; off; off >>= 1) {
            f32x4 o = shfl_xor4(cm, off);
#pragma unroll
            for (int i = 0; i < 4; i++) cm[i] = fmaxf(cm[i], o[i]);
        }
        f32x4 cp;
#pragma unroll
        for (int i = 0; i < 4; i++) cp[i] = __expf(e4[i] - cm[i]);
#pragma unroll
        for (int off = 32; off; off >>= 1) cp += shfl_xor4(cp, off);
#pragma unroll
        for (int i = 0; i < 4; i++) {
            float mn = fmaxf(m4[i], cm[i]);
            s4[i] = s4[i] * __expf(m4[i] - mn) + cp[i] * __expf(cm[i] - mn);
            m4[i] = mn;
        }
    }
#pragma unroll
    for (int i = 0; i < 4; i++) s4[i] += 1e-16f;

    // ---- gather (alpha in LDS, src via register shfl, unrolled independent loads)
    int hh = l >> 4, lr = l & 15;
    f32x4 a0 = {0, 0, 0, 0}, a1 = {0, 0, 0, 0};
    for (int t0 = 0; t0 < deg; t0 += 64) {
        int tl = min(64, deg - t0);
        int src; f32x4 e4;
        if (t0 == 0) { src = srcF; e4 = e4F; }
        else {
            src = (l < tl) ? csr[e0 + t0 + l] : 0;
            if (l < tl) {
                f32x4 ssv = *(const f32x4*)&ss1[(size_t)src * 4];
#pragma unroll
                for (int i = 0; i < 4; i++) {
                    float v = ssv[i] + sdv4[i];
                    e4[i] = (v > 0.f) ? v : 0.2f * v;
                }
            } else {
#pragma unroll
                for (int i = 0; i < 4; i++) e4[i] = -1e30f;
            }
        }
        f32x4 al4;
#pragma unroll
        for (int i = 0; i < 4; i++) al4[i] = __expf(e4[i] - m4[i]) / s4[i];
        *(f32x4*)&alds[wv][l][0] = al4;
#pragma unroll 4
        for (int k = 0; k < tl; k++) {
            int s = __shfl(src, k);
            float al = alds[wv][k][hh];
            const float* hp = h1 + (size_t)s * 512 + hh * 128 + lr * 8;
            a0 += al * *(const f32x4*)hp;
            a1 += al * *(const f32x4*)(hp + 4);
        }
    }

    // ---- head mean + LN + relu
    a0 += shfl_xor4(a0, 16); a1 += shfl_xor4(a1, 16);
    a0 += shfl_xor4(a0, 32); a1 += shfl_xor4(a1, 32);
    f32x4 v0 = a0 * 0.25f + *(const f32x4*)&b1[lr * 8];
    f32x4 v1 = a1 * 0.25f + *(const f32x4*)&b1[lr * 8 + 4];
    float s1 = v0[0] + v0[1] + v0[2] + v0[3] + v1[0] + v1[1] + v1[2] + v1[3];
#pragma unroll
    for (int off = 8; off; off >>= 1) s1 += __shfl_xor(s1, off);
    float mu = s1 * (1.f / 128.f);
    f32x4 d0 = v0 - mu, d1 = v1 - mu;
    float s2 = d0[0]*d0[0] + d0[1]*d0[1] + d0[2]*d0[2] + d0[3]*d0[3] +
               d1[0]*d1[0] + d1[1]*d1[1] + d1[2]*d1[2] + d1[3]*d1[3];
#pragma unroll
    for (int off = 8; off; off >>= 1) s2 += __shfl_xor(s2, off);
    float rs = rsqrtf(s2 * (1.f / 128.f) + 1e-5f);
    if (l < 16) {
        f32x4 g4a = *(const f32x4*)&g1[lr * 8], g4b = *(const f32x4*)&g1[lr * 8 + 4];
        f32x4 e4a = *(const f32x4*)&be1[lr * 8], e4b = *(const f32x4*)&be1[lr * 8 + 4];
        f32x4 y0, y1;
#pragma unroll
        for (int j = 0; j < 4; j++) {
            y0[j] = fmaxf(d0[j] * rs * g4a[j] + e4a[j], 0.f);
            y1[j] = fmaxf(d1[j] * rs * g4b[j] + e4b[j], 0.f);
        }
        *(f32x4*)(x1 + (size_t)n * 128 + lr * 8) = y0;
        *(f32x4*)(x1 + (size_t)n * 128 + lr * 8 + 4) = y1;
    }
}

// ================================================================ GCN1 agg v2: wave-per-node, shfl-broadcast
__global__ __launch_bounds__(256) void gcn1_agg_k(
    const float* __restrict__ hg1, const float* __restrict__ dis, const float* __restrict__ bg1,
    const int* __restrict__ rp, const int* __restrict__ csr, float* __restrict__ x1g, int N) {
    int t = threadIdx.x, l = t & 63, wv = t >> 6;
    int n = blockIdx.x * 4 + wv;
    if (n >= N) return;
    int e0 = rp[n], deg = rp[n + 1] - e0;
    float dn = dis[n];
    int ep = l >> 5, c4 = (l & 31) * 4;
    f32x4 acc = {0, 0, 0, 0};
    for (int t0 = 0; t0 < deg; t0 += 64) {
        int tl = min(64, deg - t0);
        int src = (l < tl) ? csr[e0 + t0 + l] : 0;
        float w = (l < tl) ? dis[src] * dn : 0.f;
#pragma unroll 4
        for (int k = ep; k < tl; k += 2) {
            int s = __shfl(src, k);
            float ww = __shfl(w, k);
            acc += ww * *(const f32x4*)(hg1 + (size_t)s * 128 + c4);
        }
    }
    acc += shfl_xor4(acc, 32);
    if (l < 32) {
        f32x4 b4 = *(const f32x4*)&bg1[c4];
        f32x4 y;
#pragma unroll
        for (int j = 0; j < 4; j++) y[j] = fmaxf(acc[j] + b4[j], 0.f);
        *(f32x4*)(x1g + (size_t)n * 128 + c4) = y;
    }
}

// ================================================================ GAT2 agg v2 (H=2, C=64): wave-per-node
__global__ __launch_bounds__(256) void gat2_agg_k(
    const float* __restrict__ h2, const float* __restrict__ ss2, const float* __restrict__ sd2,
    const float* __restrict__ b2, const float* __restrict__ g2, const float* __restrict__ be2,
    const int* __restrict__ rp, const int* __restrict__ csr, float* __restrict__ x2, int N) {
    __shared__ float alds[4][64][2];
    int t = threadIdx.x, l = t & 63, wv = t >> 6;
    int n = blockIdx.x * 4 + wv;
    if (n >= N) return;
    int e0 = rp[n], deg = rp[n + 1] - e0;
    float2 sdv = *(const float2*)&sd2[n * 2];

    float m0 = -1e30f, m1 = -1e30f, sA = 0.f, sB = 0.f;
    int srcF = 0; float eaF = 0.f, ebF = 0.f;
    for (int t0 = 0; t0 < deg; t0 += 64) {
        int tl = min(64, deg - t0);
        int src = (l < tl) ? csr[e0 + t0 + l] : 0;
        float ea = -1e30f, eb = -1e30f;
        if (l < tl) {
            float2 ssv = *(const float2*)&ss2[(size_t)src * 2];
            ea = ssv.x + sdv.x; ea = (ea > 0.f) ? ea : 0.2f * ea;
            eb = ssv.y + sdv.y; eb = (eb > 0.f) ? eb : 0.2f * eb;
        }
        if (t0 == 0) { srcF = src; eaF = ea; ebF = eb; }
        float cm0 = ea, cm1 = eb;
#pragma unroll
        for (int off = 32; off; off >>= 1) {
            cm0 = fmaxf(cm0, __shfl_xor(cm0, off));
            cm1 = fmaxf(cm1, __shfl_xor(cm1, off));
        }
        float cp0 = __expf(ea - cm0), cp1 = __expf(eb - cm1);
#pragma unroll
        for (int off = 32; off; off >>= 1) {
            cp0 += __shfl_xor(cp0, off);
            cp1 += __shfl_xor(cp1, off);
        }
        float mn0 = fmaxf(m0, cm0);
        sA = sA * __expf(m0 - mn0) + cp0 * __expf(cm0 - mn0);
        m0 = mn0;
        float mn1 = fmaxf(m1, cm1);
        sB = sB * __expf(m1 - mn1) + cp1 * __expf(cm1 - mn1);
        m1 = mn1;
    }
    sA += 1e-16f; sB += 1e-16f;

    int hh = l >> 5, c2 = (l & 31) * 2;
    float a0 = 0.f, a1 = 0.f;
    for (int t0 = 0; t0 < deg; t0 += 64) {
        int tl = min(64, deg - t0);
        int src; float ea, eb;
        if (t0 == 0) { src = srcF; ea = eaF; eb = ebF; }
        else {
            src = (l < tl) ? csr[e0 + t0 + l] : 0;
            ea = -1e30f; eb = -1e30f;
            if (l < tl) {
                float2 ssv = *(const float2*)&ss2[(size_t)src * 2];
                ea = ssv.x + sdv.x; ea = (ea > 0.f) ? ea : 0.2f * ea;
                eb = ssv.y + sdv.y; eb = (eb > 0.f) ? eb : 0.2f * eb;
            }
        }
        alds[wv][l][0] = __expf(ea - m0) / sA;
        alds[wv][l][1] = __expf(eb - m1) / sB;
#pragma unroll 4
        for (int k = 0; k < tl; k++) {
            int s = __shfl(src, k);
            float al = alds[wv][k][hh];
            float2 hv = *(const float2*)(h2 + (size_t)s * 128 + hh * 64 + c2);
            a0 += al * hv.x;
            a1 += al * hv.y;
        }
    }
    a0 += __shfl_xor(a0, 32);
    a1 += __shfl_xor(a1, 32);
    float v0 = a0 * 0.5f + b2[c2];
    float v1 = a1 * 0.5f + b2[c2 + 1];
    float s1 = v0 + v1;
#pragma unroll
    for (int off = 16; off; off >>= 1) s1 += __shfl_xor(s1, off);
    float mu = s1 * (1.f / 64.f);
    float d0 = v0 - mu, d1 = v1 - mu;
    float s2 = d0 * d0 + d1 * d1;
#pragma unroll
    for (int off = 16; off; off >>= 1) s2 += __shfl_xor(s2, off);
    float rs = rsqrtf(s2 * (1.f / 64.f) + 1e-5f);
    if (l < 32) {
        float y0 = fmaxf(d0 * rs * g2[c2] + be2[c2], 0.f);
        float y1 = fmaxf(d1 * rs * g2[c2 + 1] + be2[c2 + 1], 0.f);
        float2 y = {y0, y1};
        *(float2*)(x2 + (size_t)n * 64 + c2) = y;
    }
}

// ================================================================ final fused (round-7 proven)
__global__ __launch_bounds__(256) void final_fused_k(
    const float* __restrict__ hg2, const float* __restrict__ dis, const float* __restrict__ bg2,
    const int* __restrict__ rp, const int* __restrict__ csr_src,
    const float* __restrict__ x1g, const float* __restrict__ Wf, const float* __restrict__ bf,
    const float* __restrict__ skip, const float* __restrict__ g3, const float* __restrict__ be3,
    const float* __restrict__ Wc1, const float* __restrict__ bc1, const float* __restrict__ gbn,
    const float* __restrict__ bbn, const float* __restrict__ rmb, const float* __restrict__ rvb,
    const float* __restrict__ Wc2, const float* __restrict__ bc2, float* __restrict__ out, int N) {
    int wv = threadIdx.x >> 6;
    int t  = threadIdx.x & 63;
    int n = blockIdx.x * 4 + wv;
    __shared__ __align__(16) float cat_s[4][192];
    __shared__ float fbuf_s[4][64];
    __shared__ float hbuf_s[4][32];
    if (n >= N) return;

    int e0 = rp[n], deg = rp[n + 1] - e0;
    float dn = dis[n];
    int ep = t >> 4, o = (t & 15) * 4;
    f32x4 acc = {0, 0, 0, 0};
    for (int k = ep; k < deg; k += 4) {
        int s = csr_src[e0 + k];
        f32x4 v = *(const f32x4*)(hg2 + (size_t)s * 64 + o);
        acc += (dis[s] * dn) * v;
    }
    acc += shfl_xor4(acc, 32);
    acc += shfl_xor4(acc, 16);
    if (t < 16) {
        f32x4 b4 = *(const f32x4*)&bg2[o];
        f32x4 xv;
#pragma unroll
        for (int i = 0; i < 4; i++) xv[i] = fmaxf(acc[i] + b4[i], 0.f);
        *(f32x4*)&cat_s[wv][128 + o] = xv;
    }
    if (t < 32) *(f32x4*)&cat_s[wv][t * 4] = *(const f32x4*)(x1g + (size_t)n * 128 + t * 4);
    float fa = bf[t];
    const float* cat = cat_s[wv];
    for (int j = 0; j < 192; j++) fa += cat[j] * Wf[j * 64 + t];
    fa = fmaxf(fa, 0.f) + skip[(size_t)n * 64 + t];
    float t1 = fa;
#pragma unroll
    for (int off = 1; off < 64; off <<= 1) t1 += __shfl_xor(t1, off);
    float mu = t1 * (1.f / 64.f);
    float d = fa - mu;
    float t2 = d * d;
#pragma unroll
    for (int off = 1; off < 64; off <<= 1) t2 += __shfl_xor(t2, off);
    float var = t2 * (1.f / 64.f);
    fbuf_s[wv][t] = d * rsqrtf(var + 1e-5f) * g3[t] + be3[t];
    if (t < 32) {
        float a = bc1[t];
        for (int j = 0; j < 64; j++) a += fbuf_s[wv][j] * Wc1[j * 32 + t];
        a = (a - rmb[t]) * rsqrtf(rvb[t] + 1e-5f) * gbn[t] + bbn[t];
        hbuf_s[wv][t] = fmaxf(a, 0.f);
    }
    if (t < 5) {
        float a = bc2[t];
        for (int j = 0; j < 32; j++) a += hbuf_s[wv][j] * Wc2[j * 5 + t];
        out[(size_t)n * 5 + t] = a;
    }
}

// ================================================================ launch
extern "C" void kernel_launch(void* const* d_in, const int* in_sizes, int n_in,
                              void* d_out, int out_size, void* d_ws, size_t ws_size,
                              hipStream_t stream) {
    const float* x   = (const float*)d_in[0];
    const int*   ei  = (const int*)d_in[1];
    const float* gin = (const float*)d_in[2];
    const float* bti = (const float*)d_in[3];
    const float* rmi = (const float*)d_in[4];
    const float* rvi = (const float*)d_in[5];
    const float* W1  = (const float*)d_in[6];
    const float* as1 = (const float*)d_in[7];
    const float* ad1 = (const float*)d_in[8];
    const float* b1  = (const float*)d_in[9];
    const float* Wg1 = (const float*)d_in[10];
    const float* bg1 = (const float*)d_in[11];
    const float* W2  = (const float*)d_in[12];
    const float* as2 = (const float*)d_in[13];
    const float* ad2 = (const float*)d_in[14];
    const float* b2  = (const float*)d_in[15];
    const float* Wg2 = (const float*)d_in[16];
    const float* bg2 = (const float*)d_in[17];
    const float* Ws  = (const float*)d_in[18];
    const float* bs  = (const float*)d_in[19];
    const float* Wf  = (const float*)d_in[20];
    const float* bf  = (const float*)d_in[21];
    const float* g1  = (const float*)d_in[22];
    const float* be1 = (const float*)d_in[23];
    const float* g2  = (const float*)d_in[24];
    const float* be2 = (const float*)d_in[25];
    const float* g3  = (const float*)d_in[26];
    const float* be3 = (const float*)d_in[27];
    const float* Wc1 = (const float*)d_in[28];
    const float* bc1 = (const float*)d_in[29];
    const float* gbn = (const float*)d_in[30];
    const float* bbn = (const float*)d_in[31];
    const float* rmb = (const float*)d_in[32];
    const float* rvb = (const float*)d_in[33];
    const float* Wc2 = (const float*)d_in[34];
    const float* bc2 = (const float*)d_in[35];
    float* out = (float*)d_out;

    const int N = in_sizes[0] / F_IN;          // 20000
    const int E0 = in_sizes[1] / 2;            // 160000
    const int Etot = E0 + N;                   // 180000
    const int Mpad = 20096;                    // 157*128

    // ---- workspace carve-up (round-6 proven aliasing)
    char* wp = (char*)d_ws;
    auto alloc = [&](size_t bytes) -> void* {
        void* p = (void*)wp;
        wp += (bytes + 255) & ~(size_t)255;
        return p;
    };
    float* h1   = (float*)alloc((size_t)N * 512 * 4);     // aliased after GAT1 agg
    ushort* Ah  = (ushort*)alloc((size_t)Mpad * 512 * 2); // dead after GEMM -> x1 lives here
    ushort* Al  = (ushort*)alloc((size_t)Mpad * 512 * 2);
    ushort* Bth = (ushort*)alloc((size_t)640 * 512 * 2);
    ushort* Btl = (ushort*)alloc((size_t)640 * 512 * 2);
    float* skip = (float*)alloc((size_t)N * 64 * 4);
    float* ss1  = (float*)alloc((size_t)N * 4 * 4);
    float* sd1  = (float*)alloc((size_t)N * 4 * 4);
    float* ss2  = (float*)alloc((size_t)N * 2 * 4);
    float* sd2  = (float*)alloc((size_t)N * 2 * 4);
    float* dis  = (float*)alloc((size_t)N * 4);
    float* sc   = (float*)alloc((size_t)F_IN * 4);
    float* sh   = (float*)alloc((size_t)F_IN * 4);
    int* deg    = (int*)alloc((size_t)N * 4);
    int* rp     = (int*)alloc((size_t)(N + 1) * 4);
    int* fp     = (int*)alloc((size_t)(N + 1) * 4);
    int* csr    = (int*)alloc((size_t)Etot * 4);
    // aliases inside h1 (h1 dead after gat1_agg)
    float* hg1 = h1;                    // N*128
    float* x1g = h1 + (size_t)N * 128;  // N*128
    float* h2  = h1 + (size_t)N * 256;  // N*128
    float* x2  = h1 + (size_t)N * 384;  // N*64
    float* hg2 = h1 + (size_t)N * 448;  // N*64
    // alias inside Ah (dead after mfma_gemm)
    float* x1  = (float*)Ah;            // N*128

    // ---- CSR build + BN prep + splits
    zero_int_k<<<(N + 255) / 256, 256, 0, stream>>>(deg, N);
    hist_k<<<(Etot + 255) / 256, 256, 0, stream>>>(ei, E0, N, deg);
    scan_k<<<1, 1024, 0, stream>>>(deg, rp, fp, dis, N, Etot);
    scatter_k<<<(Etot + 255) / 256, 256, 0, stream>>>(ei, E0, N, fp, csr);
    bnprep_k<<<2, 256, 0, stream>>>(gin, bti, rmi, rvi, sc, sh, F_IN);
    splitA_k<<<(int)(((size_t)Mpad * 512 / 4 + 255) / 256), 256, 0, stream>>>(x, sc, sh, Ah, Al, N, Mpad);
    splitBt_k<<<dim3(10, 8), 256, 0, stream>>>(W1, Ws, Bth, Btl);

    // ---- fused GEMM: [h1 | skip] + GAT1 scores
    mfma_gemm_k<<<785, 256, 0, stream>>>(Ah, Al, Bth, Btl, bs, as1, ad1, h1, skip, ss1, sd1, N, 512);

    // ---- GAT1 agg (new) -> x1
    gat1_agg_k<<<(N + 3) / 4, 256, 0, stream>>>(h1, ss1, sd1, b1, g1, be1, rp, csr, x1, N);

    // ---- GCN1
    rowgemm_k<128, 128, false><<<1280, 128, 0, stream>>>(x1, Wg1, hg1, nullptr, nullptr, nullptr, nullptr, N);
    gcn1_agg_k<<<(N + 3) / 4, 256, 0, stream>>>(hg1, dis, bg1, rp, csr, x1g, N);

    // ---- GAT2 (scores fused into rowgemm)
    rowgemm_k<128, 128, true><<<1280, 128, 0, stream>>>(x1g, W2, h2, as2, ad2, ss2, sd2, N);
    gat2_agg_k<<<(N + 3) / 4, 256, 0, stream>>>(h2, ss2, sd2, b2, g2, be2, rp, csr, x2, N);

    // ---- GCN2 dense part
    rowgemm_k<64, 64, false><<<1280, 64, 0, stream>>>(x2, Wg2, hg2, nullptr, nullptr, nullptr, nullptr, N);

    // ---- GCN2 agg + fusion + LN + classifier
    final_fused_k<<<(N + 3) / 4, 256, 0, stream>>>(hg2, dis, bg2, rp, csr, x1g, Wf, bf, skip, g3, be3,
                                                   Wc1, bc1, gbn, bbn, rmb, rvb, Wc2, bc2, out, N);
}